// Round 6
// baseline (279.992 us; speedup 1.0000x reference)
//
#include <hip/hip_runtime.h>

#define EMBED 1024
#define NH 16
#define HS 64
#define SEQT 2048
#define NB 4
// tokens M = NB*SEQT = 8192

typedef unsigned short u16;
typedef unsigned int u32;
typedef __attribute__((ext_vector_type(8))) __bf16 bf16x8;
typedef __attribute__((ext_vector_type(4))) float f32x4;
typedef __attribute__((ext_vector_type(4))) unsigned short u16x4;

__device__ __forceinline__ u16 f2bf(float f) {
  __bf16 h = (__bf16)f;  // native v_cvt (RNE); pairs fuse to v_cvt_pk_bf16_f32
  return __builtin_bit_cast(u16, h);
}

__device__ __forceinline__ void gload_lds16(const void* g, void* l) {
  __builtin_amdgcn_global_load_lds((const __attribute__((address_space(1))) void*)g,
                                   (__attribute__((address_space(3))) void*)l, 16, 0, 0);
}

#define MFMA16(a, b, c) __builtin_amdgcn_mfma_f32_16x16x32_bf16(a, b, c, 0, 0, 0)
#define LDS_FENCE() asm volatile("" ::: "memory")

// ---------------- fp32 -> bf16 convert (x) ----------------
__global__ void cvt_x(const float* __restrict__ in, u16* __restrict__ out) {
  int i = (blockIdx.x * 256 + threadIdx.x) * 4;
  float4 v = *(const float4*)(in + i);
  u16x4 o;
  o[0] = f2bf(v.x); o[1] = f2bf(v.y); o[2] = f2bf(v.z); o[3] = f2bf(v.w);
  *(u16x4*)(out + i) = o;
}

// ---------------- weight transpose + convert: w[k][n] fp32 -> wt[n][k] bf16 ----------------
__global__ void wtrans(const float* __restrict__ w0, const float* __restrict__ w1,
                       const float* __restrict__ w2, const float* __restrict__ w3,
                       u16* __restrict__ t0, u16* __restrict__ t1,
                       u16* __restrict__ t2, u16* __restrict__ t3) {
  __shared__ float tile[32][33];
  const float* w; u16* t;
  switch (blockIdx.z) {
    case 0: w = w0; t = t0; break;
    case 1: w = w1; t = t1; break;
    case 2: w = w2; t = t2; break;
    default: w = w3; t = t3; break;
  }
  int n0 = blockIdx.x * 32, k0 = blockIdx.y * 32;
  int tx = threadIdx.x, ty = threadIdx.y;
#pragma unroll
  for (int r = 0; r < 4; ++r)
    tile[ty + r * 8][tx] = w[(size_t)(k0 + ty + r * 8) * EMBED + n0 + tx];
  __syncthreads();
#pragma unroll
  for (int r = 0; r < 4; ++r)
    t[(size_t)(n0 + ty + r * 8) * EMBED + k0 + tx] = f2bf(tile[tx][ty + r * 8]);
}

// ======== 8-wave phase-interleaved GEMM core (T2+T3+T4+T5) ========
// BM x 256 tile, BK=64, 8 waves (2 x 4), per-wave out = (BM/2) x 64.
// Per K-tile: 4 quadrant-phases; af-half / bfr-pair each ds-loaded once and reused.
// Staging for tile t+1 spread across phases (2 gloads/phase); counted vmcnt(2|1)
// once per K-tile at phase 0 (vmcnt(0) only at the last tile). Raw s_barrier
// (no compiler vmcnt drain) + IR fence + sched_barrier per barrier.
template <int BM, int MREP>
__device__ __forceinline__ void gemm_core(
    const u16* __restrict__ A, const u16* __restrict__ Bt, int m0, int n0,
    u16 (&As)[2][BM * 64], u16 (&Bs)[2][256 * 64],
    f32x4 (&acc)[MREP][4], int lane, int wid) {
  const int tid = wid * 64 + lane;
  const int lr = lane & 15, lg = lane >> 4;
  const int arow = tid >> 3;                      // 0..63
  const int csw = ((tid & 7) ^ (arow & 7)) * 8;   // pre-swizzled source chunk
  const int ldst = arow * 64 + (tid & 7) * 8;     // linear LDS dest (= base + lane*16B)
  const int wrb = (wid >> 2) * (BM / 2);
  const int wcb = (wid & 3) * 64;
  const u16* Aa = A + (size_t)m0 * EMBED;
  const u16* Bb = Bt + (size_t)n0 * EMBED;

  auto stage = [&](const u16* src, u16* dst, int j, int k0) {
    gload_lds16(src + (size_t)(arow + 64 * j) * EMBED + k0 + csw, dst + j * 4096 + ldst);
  };
  auto rd = [&](const u16* buf, int row, int kk) -> bf16x8 {
    return *(const bf16x8*)(buf + row * 64 + (((kk * 4 + lg) ^ (lr & 7)) * 8));
  };

  // prologue: stage tile 0 into buffer 0 (same issue count as steady state)
#pragma unroll
  for (int j = 0; j < BM / 64; ++j) stage(Aa, As[0], j, 0);
#pragma unroll
  for (int j = 0; j < 4; ++j) stage(Bb, Bs[0], j, 0);

  for (int t = 0; t < 16; ++t) {
    const int kn = (t + 1) * 64;
    u16* Ac = (t & 1) ? As[1] : As[0];
    u16* Bc = (t & 1) ? Bs[1] : Bs[0];
    u16* An = (t & 1) ? As[0] : As[1];
    u16* Bn = (t & 1) ? Bs[0] : Bs[1];
    const bool pf = (t < 15);

    bf16x8 af[MREP / 2][2], bf0[2][2], bf1[2][2];

    // ---- phase 0: quadrant (mh0, nh0); stage A(0[,1]); counted vmcnt ----
    if (pf) {
      stage(Aa, An, 0, kn);
      if constexpr (BM == 256) {
        stage(Aa, An, 1, kn);
        asm volatile("s_waitcnt vmcnt(2)" ::: "memory");
      } else {
        asm volatile("s_waitcnt vmcnt(1)" ::: "memory");
      }
    } else {
      asm volatile("s_waitcnt vmcnt(0)" ::: "memory");
    }
    __builtin_amdgcn_sched_barrier(0);
    __builtin_amdgcn_s_barrier();   // publish tile t (all waves' stages landed)
    LDS_FENCE();
#pragma unroll
    for (int mi = 0; mi < MREP / 2; ++mi)
#pragma unroll
      for (int kk = 0; kk < 2; ++kk) af[mi][kk] = rd(Ac, wrb + mi * 16 + lr, kk);
#pragma unroll
    for (int ni = 0; ni < 2; ++ni)
#pragma unroll
      for (int kk = 0; kk < 2; ++kk) bf0[ni][kk] = rd(Bc, wcb + ni * 16 + lr, kk);
    __builtin_amdgcn_s_setprio(1);
#pragma unroll
    for (int mi = 0; mi < MREP / 2; ++mi)
#pragma unroll
      for (int ni = 0; ni < 2; ++ni) {
        acc[mi][ni] = MFMA16(af[mi][0], bf0[ni][0], acc[mi][ni]);
        acc[mi][ni] = MFMA16(af[mi][1], bf0[ni][1], acc[mi][ni]);
      }
    __builtin_amdgcn_s_setprio(0);
    __builtin_amdgcn_s_barrier();
    LDS_FENCE();

    // ---- phase 1: quadrant (mh0, nh1); stage A(rest) ----
    if (pf) {
      if constexpr (BM == 256) { stage(Aa, An, 2, kn); stage(Aa, An, 3, kn); }
      else stage(Aa, An, 1, kn);
    }
#pragma unroll
    for (int ni = 0; ni < 2; ++ni)
#pragma unroll
      for (int kk = 0; kk < 2; ++kk) bf1[ni][kk] = rd(Bc, wcb + (2 + ni) * 16 + lr, kk);
    __builtin_amdgcn_s_setprio(1);
#pragma unroll
    for (int mi = 0; mi < MREP / 2; ++mi)
#pragma unroll
      for (int ni = 0; ni < 2; ++ni) {
        acc[mi][2 + ni] = MFMA16(af[mi][0], bf1[ni][0], acc[mi][2 + ni]);
        acc[mi][2 + ni] = MFMA16(af[mi][1], bf1[ni][1], acc[mi][2 + ni]);
      }
    __builtin_amdgcn_s_setprio(0);
    __builtin_amdgcn_s_barrier();
    LDS_FENCE();

    // ---- phase 2: quadrant (mh1, nh1); stage B(0,1); af overwritten with half 1 ----
    if (pf) { stage(Bb, Bn, 0, kn); stage(Bb, Bn, 1, kn); }
#pragma unroll
    for (int mi = 0; mi < MREP / 2; ++mi)
#pragma unroll
      for (int kk = 0; kk < 2; ++kk)
        af[mi][kk] = rd(Ac, wrb + (MREP / 2 + mi) * 16 + lr, kk);
    __builtin_amdgcn_s_setprio(1);
#pragma unroll
    for (int mi = 0; mi < MREP / 2; ++mi)
#pragma unroll
      for (int ni = 0; ni < 2; ++ni) {
        acc[MREP / 2 + mi][2 + ni] = MFMA16(af[mi][0], bf1[ni][0], acc[MREP / 2 + mi][2 + ni]);
        acc[MREP / 2 + mi][2 + ni] = MFMA16(af[mi][1], bf1[ni][1], acc[MREP / 2 + mi][2 + ni]);
      }
    __builtin_amdgcn_s_setprio(0);
    __builtin_amdgcn_s_barrier();
    LDS_FENCE();

    // ---- phase 3: quadrant (mh1, nh0); stage B(2,3); no ds_reads (regs reused) ----
    if (pf) { stage(Bb, Bn, 2, kn); stage(Bb, Bn, 3, kn); }
    __builtin_amdgcn_s_setprio(1);
#pragma unroll
    for (int mi = 0; mi < MREP / 2; ++mi)
#pragma unroll
      for (int ni = 0; ni < 2; ++ni) {
        acc[MREP / 2 + mi][ni] = MFMA16(af[mi][0], bf0[ni][0], acc[MREP / 2 + mi][ni]);
        acc[MREP / 2 + mi][ni] = MFMA16(af[mi][1], bf0[ni][1], acc[MREP / 2 + mi][ni]);
      }
    __builtin_amdgcn_s_setprio(0);
    __builtin_amdgcn_s_barrier();   // protects buffer t+1 region from tile t+2 stages
    LDS_FENCE();
  }
}

// ---------------- fused QKV projection: [8192x1024] x [1024x3072], 256x256 tile ----------------
__global__ __launch_bounds__(512, 2) void gemm_qkv(
    const u16* __restrict__ A, const u16* __restrict__ Bt,   // Bt = [3072][1024] (wq|wk|wv)^T
    const float* __restrict__ bq, const float* __restrict__ bk, const float* __restrict__ bv,
    u16* __restrict__ qo, u16* __restrict__ ko, u16* __restrict__ vto) {
  __shared__ __align__(16) u16 As[2][256 * 64];   // 64 KiB
  __shared__ __align__(16) u16 Bs[2][256 * 64];   // 64 KiB
  const int bid = blockIdx.x;
  const int swz = (bid & 7) * 48 + (bid >> 3);    // bijective XCD swizzle (384 = 8*48)
  const int bm = swz / 12, bn = swz % 12;
  const int m0 = bm * 256, n0 = bn * 256;
  const int lane = threadIdx.x & 63, wid = threadIdx.x >> 6;
  const int lr = lane & 15, lg = lane >> 4;
  const int z = n0 >> 10;  // 0=q 1=k 2=v (256 | 1024 -> block-uniform)
  const float* bias = (z == 0) ? bq : ((z == 1) ? bk : bv);
  const float sc = (z == 0) ? 0.18033688011112042f : 1.0f;  // hs^-0.5 * log2e folded into Q

  f32x4 acc[8][4];
  const f32x4 zero = {0.f, 0.f, 0.f, 0.f};
#pragma unroll
  for (int m = 0; m < 8; ++m)
#pragma unroll
    for (int n = 0; n < 4; ++n) acc[m][n] = zero;

  gemm_core<256, 8>(A, Bt, m0, n0, As, Bs, acc, lane, wid);

  const int wrb = (wid >> 2) * 128, wcb = (wid & 3) * 64;
#pragma unroll
  for (int n = 0; n < 4; ++n) {
    int col = n0 + wcb + n * 16 + lr;
    int lcol = col & 1023;
    float bv_ = bias[lcol];
    int h = lcol >> 6, d = lcol & 63;
#pragma unroll
    for (int m = 0; m < 8; ++m) {
      int r0 = m0 + wrb + m * 16 + lg * 4;
      int b_ = r0 >> 11, t_ = r0 & 2047;
      if (z < 2) {
        u16* dst = (z == 0) ? qo : ko;
#pragma unroll
        for (int i = 0; i < 4; ++i)
          dst[(((size_t)(b_ * NH + h)) * SEQT + t_ + i) * HS + d] = f2bf((acc[m][n][i] + bv_) * sc);
      } else {
        u16x4 v;
#pragma unroll
        for (int i = 0; i < 4; ++i) v[i] = f2bf(acc[m][n][i] + bv_);
        *(u16x4*)(vto + (((size_t)(b_ * NH + h)) * HS + d) * SEQT + t_) = v;
      }
    }
  }
}

// ---------------- output projection: [8192x1024] x [1024x1024], 128x256 tile -> fp32 ----------
__global__ __launch_bounds__(512, 2) void gemm_out(
    const u16* __restrict__ A, const u16* __restrict__ wot,
    const float* __restrict__ bo, float* __restrict__ out) {
  __shared__ __align__(16) u16 As[2][128 * 64];   // 32 KiB
  __shared__ __align__(16) u16 Bs[2][256 * 64];   // 64 KiB
  const int bid = blockIdx.x;
  const int swz = (bid & 7) * 32 + (bid >> 3);    // 256 = 8*32
  const int bm = swz >> 2, bn = swz & 3;
  const int m0 = bm * 128, n0 = bn * 256;
  const int lane = threadIdx.x & 63, wid = threadIdx.x >> 6;
  const int lr = lane & 15, lg = lane >> 4;

  f32x4 acc[4][4];
  const f32x4 zero = {0.f, 0.f, 0.f, 0.f};
#pragma unroll
  for (int m = 0; m < 4; ++m)
#pragma unroll
    for (int n = 0; n < 4; ++n) acc[m][n] = zero;

  gemm_core<128, 4>(A, wot, m0, n0, As, Bs, acc, lane, wid);

  const int wrb = (wid >> 2) * 64, wcb = (wid & 3) * 64;
#pragma unroll
  for (int n = 0; n < 4; ++n) {
    int col = n0 + wcb + n * 16 + lr;
    float bv_ = bo[col];
#pragma unroll
    for (int m = 0; m < 4; ++m) {
      int r0 = m0 + wrb + m * 16 + lg * 4;
#pragma unroll
      for (int i = 0; i < 4; ++i)
        out[(size_t)(r0 + i) * EMBED + col] = acc[m][n][i] + bv_;
    }
  }
}

// ---------------- flash attention v4 (unchanged from R4) ----------------
// 4 waves/block, QBLK=32/wave, KVBLK=64, single q-tile/block (1024 blocks,
// longest-first), 3 blocks/CU, 2-phase prefetch, XOR-swizzled K/V/P LDS,
// swapped QK^T, defer-max (THR=8 log2), setprio around MFMA clusters.
__global__ __launch_bounds__(256, 3) void flash(
    const u16* __restrict__ q, const u16* __restrict__ k,
    const u16* __restrict__ vt, u16* __restrict__ attnb) {
  __shared__ __align__(16) u16 Ks[2][4096];   // [kv=64][d=64] swizzled
  __shared__ __align__(16) u16 Vs[2][4096];   // [d=64][kv=64] swizzled
  __shared__ __align__(16) u16 Pl[4][2048];   // per-wave [q=32][kv=64] swizzled
  const int tid = threadIdx.x, lane = tid & 63, wid = tid >> 6;
  const int lr = lane & 15, lg = lane >> 4;
  const int g = blockIdx.x >> 6, pair = blockIdx.x & 63;  // same-pair blocks share an XCD
  const int qtile = 15 - g;                               // longest tiles dispatch first
  const u16* Qh = q + (size_t)pair * SEQT * HS;
  const u16* Kh = k + (size_t)pair * SEQT * HS;
  const u16* Vh = vt + (size_t)pair * HS * SEQT;

  const int sr0 = wid * 16 + (lane >> 3);
  const int sc0 = (lane & 7) ^ (sr0 & 7);
  const int sr1 = sr0 + 8;
  const int sc1 = (lane & 7) ^ (sr1 & 7);
  const int koff0 = sr0 * 64 + sc0 * 8;
  const int koff1 = sr1 * 64 + sc1 * 8;
  const size_t voff0 = (size_t)sr0 * SEQT + sc0 * 8;
  const size_t voff1 = (size_t)sr1 * SEQT + sc1 * 8;

  auto STAGE = [&](int t, int b) {
    const u16* Kb = Kh + (size_t)t * 4096;
    const u16* Vb = Vh + (size_t)t * 64;
    gload_lds16(Kb + koff0, &Ks[b][wid * 1024]);
    gload_lds16(Kb + koff1, &Ks[b][wid * 1024 + 512]);
    gload_lds16(Vb + voff0, &Vs[b][wid * 1024]);
    gload_lds16(Vb + voff1, &Vs[b][wid * 1024 + 512]);
  };

  const int b_ = pair >> 4, h = pair & 15;
  const int qw = qtile * 128 + wid * 32;

  bf16x8 qf[2][2];
#pragma unroll
  for (int nq = 0; nq < 2; ++nq)
#pragma unroll
    for (int ks = 0; ks < 2; ++ks)
      qf[nq][ks] = *(const bf16x8*)(Qh + (size_t)(qw + nq * 16 + lr) * HS + ks * 32 + lg * 8);

  f32x4 o[2][4];
  const f32x4 zero = {0.f, 0.f, 0.f, 0.f};
#pragma unroll
  for (int mr = 0; mr < 2; ++mr)
#pragma unroll
    for (int nd = 0; nd < 4; ++nd) o[mr][nd] = zero;
  float mrow[2] = {-1e30f, -1e30f}, lrow[2] = {0.f, 0.f};

  const int nt = (qtile + 1) * 2;
  int cur = 0;
  STAGE(0, 0);
  __syncthreads();

  for (int t = 0; t < nt; ++t) {
    if (t + 1 < nt) STAGE(t + 1, cur ^ 1);  // prefetch: completes under compute
    const int k0 = t * 64;

    bf16x8 kf[4][2];
#pragma unroll
    for (int mf = 0; mf < 4; ++mf) {
      const int row = mf * 16 + lr;
#pragma unroll
      for (int ks = 0; ks < 2; ++ks)
        kf[mf][ks] = *(const bf16x8*)(&Ks[cur][row * 64 + ((ks * 4 + lg) ^ (lr & 7)) * 8]);
    }
    // swapped QK^T: out col = q (lane&15), row = kv (lg*4+reg)
    f32x4 s[2][4];
    __builtin_amdgcn_s_setprio(1);
#pragma unroll
    for (int nq = 0; nq < 2; ++nq)
#pragma unroll
      for (int mf = 0; mf < 4; ++mf) {
        f32x4 a = zero;
        a = MFMA16(kf[mf][0], qf[nq][0], a);
        a = MFMA16(kf[mf][1], qf[nq][1], a);
        s[nq][mf] = a;
      }
    __builtin_amdgcn_s_setprio(0);
    bf16x8 vf[4][2];
#pragma unroll
    for (int nd = 0; nd < 4; ++nd) {
      const int row = nd * 16 + lr;
#pragma unroll
      for (int ks = 0; ks < 2; ++ks)
        vf[nd][ks] = *(const bf16x8*)(&Vs[cur][row * 64 + ((ks * 4 + lg) ^ (lr & 7)) * 8]);
    }

#pragma unroll
    for (int nq = 0; nq < 2; ++nq) {
      const int qmin = qw + nq * 16;
      if (k0 + 63 > qmin) {  // wave-uniform mask skip (diagonal tiles only)
        const int ql = qmin + lr;
#pragma unroll
        for (int mf = 0; mf < 4; ++mf) {
          const int kvb = k0 + mf * 16 + lg * 4;
#pragma unroll
          for (int r = 0; r < 4; ++r)
            if (kvb + r > ql) s[nq][mf][r] = -3.0e38f;
        }
      }
      float t0 = fmaxf(fmaxf(s[nq][0][0], s[nq][0][1]), fmaxf(s[nq][0][2], s[nq][0][3]));
      float t1 = fmaxf(fmaxf(s[nq][1][0], s[nq][1][1]), fmaxf(s[nq][1][2], s[nq][1][3]));
      float t2 = fmaxf(fmaxf(s[nq][2][0], s[nq][2][1]), fmaxf(s[nq][2][2], s[nq][2][3]));
      float t3 = fmaxf(fmaxf(s[nq][3][0], s[nq][3][1]), fmaxf(s[nq][3][2], s[nq][3][3]));
      float mx = fmaxf(fmaxf(t0, t1), fmaxf(t2, t3));
      mx = fmaxf(mx, __shfl_xor(mx, 16, 64));
      mx = fmaxf(mx, __shfl_xor(mx, 32, 64));
      // T13 defer-max: only rescale when a row's max grew past 8 (log2 domain)
      if (__any(mx > mrow[nq] + 8.0f)) {
        const float mn = fmaxf(mrow[nq], mx);
        const float al = exp2f(mrow[nq] - mn);
        mrow[nq] = mn;
        lrow[nq] *= al;
        float ao[4];
#pragma unroll
        for (int r = 0; r < 4; ++r) ao[r] = __shfl(al, lg * 4 + r, 64);
#pragma unroll
        for (int nd = 0; nd < 4; ++nd)
#pragma unroll
          for (int r = 0; r < 4; ++r) o[nq][nd][r] *= ao[r];
      }
      const float mn = mrow[nq];
      float rs = 0.f;
#pragma unroll
      for (int mf = 0; mf < 4; ++mf) {
        u16x4 pk;
#pragma unroll
        for (int r = 0; r < 4; ++r) {
          const float pv = exp2f(s[nq][mf][r] - mn);
          rs += pv;
          pk[r] = f2bf(pv);
        }
        *(u16x4*)(&Pl[wid][(nq * 16 + lr) * 64 +
                           (((2 * mf + (lg >> 1)) ^ (lr & 7)) * 8 + (lg & 1) * 4)]) = pk;
      }
      rs += __shfl_xor(rs, 16, 64);
      rs += __shfl_xor(rs, 32, 64);
      lrow[nq] += rs;
    }

    bf16x8 pa[2][2];
#pragma unroll
    for (int mr = 0; mr < 2; ++mr)
#pragma unroll
      for (int ks = 0; ks < 2; ++ks)
        pa[mr][ks] = *(const bf16x8*)(&Pl[wid][(mr * 16 + lr) * 64 + ((ks * 4 + lg) ^ (lr & 7)) * 8]);
    __builtin_amdgcn_s_setprio(1);
#pragma unroll
    for (int mr = 0; mr < 2; ++mr)
#pragma unroll
      for (int nd = 0; nd < 4; ++nd) {
        o[mr][nd] = MFMA16(pa[mr][0], vf[nd][0], o[mr][nd]);
        o[mr][nd] = MFMA16(pa[mr][1], vf[nd][1], o[mr][nd]);
      }
    __builtin_amdgcn_s_setprio(0);

    __syncthreads();  // drains prefetch vmcnt + publishes next buffer
    cur ^= 1;
  }

  // epilogue: attnb[b][t][h*64+d]
#pragma unroll
  for (int mr = 0; mr < 2; ++mr) {
    const float lv = 1.0f / lrow[mr];
    float li[4];
#pragma unroll
    for (int r = 0; r < 4; ++r) li[r] = __shfl(lv, lg * 4 + r, 64);
#pragma unroll
    for (int nd = 0; nd < 4; ++nd) {
      const int d = nd * 16 + lr;
#pragma unroll
      for (int r = 0; r < 4; ++r) {
        const int t_ = qw + mr * 16 + lg * 4 + r;
        attnb[((size_t)(b_ * SEQT + t_)) * EMBED + h * 64 + d] = f2bf(o[mr][nd][r] * li[r]);
      }
    }
  }
}

extern "C" void kernel_launch(void* const* d_in, const int* in_sizes, int n_in,
                              void* d_out, int out_size, void* d_ws, size_t ws_size,
                              hipStream_t stream) {
  const float* x  = (const float*)d_in[0];
  const float* wq = (const float*)d_in[1];
  const float* bq = (const float*)d_in[2];
  const float* wk = (const float*)d_in[3];
  const float* bk = (const float*)d_in[4];
  const float* wv = (const float*)d_in[5];
  const float* bv = (const float*)d_in[6];
  const float* wo = (const float*)d_in[7];
  const float* bo = (const float*)d_in[8];
  float* out = (float*)d_out;

  char* ws = (char*)d_ws;
  const size_t XB = 16777216;      // 8192*1024*2
  const size_t WB = 2097152;       // 1024*1024*2
  const size_t QB = 16777216;
  u16* xb     = (u16*)(ws);
  u16* wqkvbt = (u16*)(ws + XB);                    // fused [3072][1024] (wq|wk|wv)^T
  u16* wobt   = (u16*)(ws + XB + 3 * WB);
  u16* qb     = (u16*)(ws + XB + 4 * WB);
  u16* kb     = (u16*)(ws + XB + 4 * WB + QB);
  u16* vtb    = (u16*)(ws + XB + 4 * WB + 2 * QB);
  u16* attnb  = (u16*)(ws + XB + 4 * WB + 3 * QB);

  hipLaunchKernelGGL(cvt_x, dim3(8192), dim3(256), 0, stream, x, xb);
  hipLaunchKernelGGL(wtrans, dim3(32, 32, 4), dim3(32, 8), 0, stream,
                     wq, wk, wv, wo,
                     wqkvbt, wqkvbt + 1048576, wqkvbt + 2097152, wobt);
  hipLaunchKernelGGL(gemm_qkv, dim3(384), dim3(512), 0, stream,
                     xb, wqkvbt, bq, bk, bv, qb, kb, vtb);
  hipLaunchKernelGGL(flash, dim3(1024), dim3(256), 0, stream, qb, kb, vtb, attnb);
  hipLaunchKernelGGL(gemm_out, dim3(256), dim3(512), 0, stream, attnb, wobt, bo, out);
}

// Round 7
// 274.772 us; speedup vs baseline: 1.0190x; 1.0190x over previous
//
#include <hip/hip_runtime.h>

#define EMBED 1024
#define NH 16
#define HS 64
#define SEQT 2048
#define NB 4
// tokens M = NB*SEQT = 8192

typedef unsigned short u16;
typedef unsigned int u32;
typedef __attribute__((ext_vector_type(8))) __bf16 bf16x8;
typedef __attribute__((ext_vector_type(4))) float f32x4;
typedef __attribute__((ext_vector_type(4))) unsigned short u16x4;

__device__ __forceinline__ u16 f2bf(float f) {
  __bf16 h = (__bf16)f;  // native v_cvt (RNE); pairs fuse to v_cvt_pk_bf16_f32
  return __builtin_bit_cast(u16, h);
}

__device__ __forceinline__ void gload_lds16(const void* g, void* l) {
  __builtin_amdgcn_global_load_lds((const __attribute__((address_space(1))) void*)g,
                                   (__attribute__((address_space(3))) void*)l, 16, 0, 0);
}

#define MFMA16(a, b, c) __builtin_amdgcn_mfma_f32_16x16x32_bf16(a, b, c, 0, 0, 0)
#define LDS_FENCE() asm volatile("" ::: "memory")

// ---------------- fp32 -> bf16 convert (x) ----------------
__global__ void cvt_x(const float* __restrict__ in, u16* __restrict__ out) {
  int i = (blockIdx.x * 256 + threadIdx.x) * 4;
  float4 v = *(const float4*)(in + i);
  u16x4 o;
  o[0] = f2bf(v.x); o[1] = f2bf(v.y); o[2] = f2bf(v.z); o[3] = f2bf(v.w);
  *(u16x4*)(out + i) = o;
}

// ---------------- weight transpose + convert: w[k][n] fp32 -> wt[n][k] bf16 ----------------
__global__ void wtrans(const float* __restrict__ w0, const float* __restrict__ w1,
                       const float* __restrict__ w2, const float* __restrict__ w3,
                       u16* __restrict__ t0, u16* __restrict__ t1,
                       u16* __restrict__ t2, u16* __restrict__ t3) {
  __shared__ float tile[32][33];
  const float* w; u16* t;
  switch (blockIdx.z) {
    case 0: w = w0; t = t0; break;
    case 1: w = w1; t = t1; break;
    case 2: w = w2; t = t2; break;
    default: w = w3; t = t3; break;
  }
  int n0 = blockIdx.x * 32, k0 = blockIdx.y * 32;
  int tx = threadIdx.x, ty = threadIdx.y;
#pragma unroll
  for (int r = 0; r < 4; ++r)
    tile[ty + r * 8][tx] = w[(size_t)(k0 + ty + r * 8) * EMBED + n0 + tx];
  __syncthreads();
#pragma unroll
  for (int r = 0; r < 4; ++r)
    t[(size_t)(n0 + ty + r * 8) * EMBED + k0 + tx] = f2bf(tile[tx][ty + r * 8]);
}

// ======== 8-wave phase-interleaved GEMM core v2 (T2+T3+T4+T5, staggered staging) ========
// BM x 256 tile, BK=64, 8 waves (2 x 4), per-wave out = (BM/2) x 64.
// Phases = (K-half kk, row-half). Staging order == consumption order:
//   B0,B1 -> B2,B3 -> A0,A2 -> A1,A3   (A0,A2 = row-half0 of both wave-row-blocks)
// so phase-0's wait covers loads issued >=2 phases earlier (L2-latency cover).
// Counted vmcnt: BM=256: vmcnt(4)@ph0 + vmcnt(4)@ph1; BM=128: vmcnt(2)@ph0.
// Never vmcnt(0) mid-loop. 3 barriers per K-tile (publish ph0, publish ph1, end).
template <int BM, int MREP>
__device__ __forceinline__ void gemm_core(
    const u16* __restrict__ A, const u16* __restrict__ Bt, int m0, int n0,
    u16 (&As)[2][BM * 64], u16 (&Bs)[2][256 * 64],
    f32x4 (&acc)[MREP][4], int lane, int wid) {
  const int tid = wid * 64 + lane;
  const int lr = lane & 15, lg = lane >> 4;
  const int arow = tid >> 3;                      // 0..63
  const int csw = ((tid & 7) ^ (arow & 7)) * 8;   // pre-swizzled source chunk
  const int ldst = arow * 64 + (tid & 7) * 8;     // linear LDS dest (= base + lane*16B)
  const int wrb = (wid >> 2) * (BM / 2);
  const int wcb = (wid & 3) * 64;
  const u16* Aa = A + (size_t)m0 * EMBED;
  const u16* Bb = Bt + (size_t)n0 * EMBED;

  auto stage = [&](const u16* src, u16* dst, int j, int k0) {
    gload_lds16(src + (size_t)(arow + 64 * j) * EMBED + k0 + csw, dst + j * 4096 + ldst);
  };
  auto rd = [&](const u16* buf, int row, int kk) -> bf16x8 {
    return *(const bf16x8*)(buf + row * 64 + (((kk * 4 + lg) ^ (lr & 7)) * 8));
  };

  // prologue: stage tile 0 in consumption order
  stage(Bb, Bs[0], 0, 0); stage(Bb, Bs[0], 1, 0);
  stage(Bb, Bs[0], 2, 0); stage(Bb, Bs[0], 3, 0);
  if constexpr (BM == 256) {
    stage(Aa, As[0], 0, 0); stage(Aa, As[0], 2, 0);
    stage(Aa, As[0], 1, 0); stage(Aa, As[0], 3, 0);
  } else {
    stage(Aa, As[0], 0, 0); stage(Aa, As[0], 1, 0);
  }

  for (int t = 0; t < 16; ++t) {
    const int kn = (t + 1) * 64;
    u16* Ac = (t & 1) ? As[1] : As[0];
    u16* Bc = (t & 1) ? Bs[1] : Bs[0];
    u16* An = (t & 1) ? As[0] : As[1];
    u16* Bn = (t & 1) ? Bs[0] : Bs[1];
    const bool pf = (t < 15);

    bf16x8 af[MREP / 2], bf[4];

    // ---- phase 0: kk=0, row-half 0; stage B0,B1(t+1); publish {B*,A0,A2}(t) ----
    if (pf) { stage(Bb, Bn, 0, kn); stage(Bb, Bn, 1, kn); }
    if constexpr (BM == 256) {
      if (pf) asm volatile("s_waitcnt vmcnt(4)" ::: "memory");
      else    asm volatile("s_waitcnt vmcnt(2)" ::: "memory");
    } else {
      if (pf) asm volatile("s_waitcnt vmcnt(2)" ::: "memory");
      else    asm volatile("s_waitcnt vmcnt(0)" ::: "memory");
    }
    __builtin_amdgcn_sched_barrier(0);
    __builtin_amdgcn_s_barrier();
    LDS_FENCE();
#pragma unroll
    for (int mi = 0; mi < MREP / 2; ++mi) af[mi] = rd(Ac, wrb + mi * 16 + lr, 0);
#pragma unroll
    for (int ni = 0; ni < 4; ++ni) bf[ni] = rd(Bc, wcb + ni * 16 + lr, 0);
    __builtin_amdgcn_s_setprio(1);
#pragma unroll
    for (int mi = 0; mi < MREP / 2; ++mi)
#pragma unroll
      for (int ni = 0; ni < 4; ++ni)
        acc[mi][ni] = MFMA16(af[mi], bf[ni], acc[mi][ni]);
    __builtin_amdgcn_s_setprio(0);

    // ---- phase 1: kk=0, row-half 1; stage B2,B3(t+1); (BM=256) publish {A1,A3}(t) ----
    if (pf) { stage(Bb, Bn, 2, kn); stage(Bb, Bn, 3, kn); }
    if constexpr (BM == 256) {
      if (pf) asm volatile("s_waitcnt vmcnt(4)" ::: "memory");
      else    asm volatile("s_waitcnt vmcnt(0)" ::: "memory");
      __builtin_amdgcn_sched_barrier(0);
      __builtin_amdgcn_s_barrier();
      LDS_FENCE();
    }
#pragma unroll
    for (int mi = 0; mi < MREP / 2; ++mi)
      af[mi] = rd(Ac, wrb + (MREP / 2 + mi) * 16 + lr, 0);
    __builtin_amdgcn_s_setprio(1);
#pragma unroll
    for (int mi = 0; mi < MREP / 2; ++mi)
#pragma unroll
      for (int ni = 0; ni < 4; ++ni)
        acc[MREP / 2 + mi][ni] = MFMA16(af[mi], bf[ni], acc[MREP / 2 + mi][ni]);
    __builtin_amdgcn_s_setprio(0);

    // ---- phase 2: kk=1, row-half 0; stage A row-half0 (t+1) ----
    if (pf) {
      if constexpr (BM == 256) { stage(Aa, An, 0, kn); stage(Aa, An, 2, kn); }
      else                     { stage(Aa, An, 0, kn); stage(Aa, An, 1, kn); }
    }
#pragma unroll
    for (int mi = 0; mi < MREP / 2; ++mi) af[mi] = rd(Ac, wrb + mi * 16 + lr, 1);
#pragma unroll
    for (int ni = 0; ni < 4; ++ni) bf[ni] = rd(Bc, wcb + ni * 16 + lr, 1);
    __builtin_amdgcn_s_setprio(1);
#pragma unroll
    for (int mi = 0; mi < MREP / 2; ++mi)
#pragma unroll
      for (int ni = 0; ni < 4; ++ni)
        acc[mi][ni] = MFMA16(af[mi], bf[ni], acc[mi][ni]);
    __builtin_amdgcn_s_setprio(0);

    // ---- phase 3: kk=1, row-half 1; stage A row-half1 (t+1, BM=256 only) ----
    if (pf) {
      if constexpr (BM == 256) { stage(Aa, An, 1, kn); stage(Aa, An, 3, kn); }
    }
#pragma unroll
    for (int mi = 0; mi < MREP / 2; ++mi)
      af[mi] = rd(Ac, wrb + (MREP / 2 + mi) * 16 + lr, 1);
    __builtin_amdgcn_s_setprio(1);
#pragma unroll
    for (int mi = 0; mi < MREP / 2; ++mi)
#pragma unroll
      for (int ni = 0; ni < 4; ++ni)
        acc[MREP / 2 + mi][ni] = MFMA16(af[mi], bf[ni], acc[MREP / 2 + mi][ni]);
    __builtin_amdgcn_s_setprio(0);
    __builtin_amdgcn_s_barrier();   // end-of-tile: all reads of cur done before next ph0 stages
    LDS_FENCE();
  }
}

// ---------------- fused QKV projection: [8192x1024] x [1024x3072], 256x256 tile ----------------
__global__ __launch_bounds__(512, 2) void gemm_qkv(
    const u16* __restrict__ A, const u16* __restrict__ Bt,   // Bt = [3072][1024] (wq|wk|wv)^T
    const float* __restrict__ bq, const float* __restrict__ bk, const float* __restrict__ bv,
    u16* __restrict__ qo, u16* __restrict__ ko, u16* __restrict__ vto) {
  __shared__ __align__(16) u16 As[2][256 * 64];   // 64 KiB
  __shared__ __align__(16) u16 Bs[2][256 * 64];   // 64 KiB
  const int bid = blockIdx.x;
  const int swz = (bid & 7) * 48 + (bid >> 3);    // bijective XCD swizzle (384 = 8*48)
  const int bm = swz / 12, bn = swz % 12;
  const int m0 = bm * 256, n0 = bn * 256;
  const int lane = threadIdx.x & 63, wid = threadIdx.x >> 6;
  const int lr = lane & 15, lg = lane >> 4;
  const int z = n0 >> 10;  // 0=q 1=k 2=v (256 | 1024 -> block-uniform)
  const float* bias = (z == 0) ? bq : ((z == 1) ? bk : bv);
  const float sc = (z == 0) ? 0.18033688011112042f : 1.0f;  // hs^-0.5 * log2e folded into Q

  f32x4 acc[8][4];
  const f32x4 zero = {0.f, 0.f, 0.f, 0.f};
#pragma unroll
  for (int m = 0; m < 8; ++m)
#pragma unroll
    for (int n = 0; n < 4; ++n) acc[m][n] = zero;

  gemm_core<256, 8>(A, Bt, m0, n0, As, Bs, acc, lane, wid);

  const int wrb = (wid >> 2) * 128, wcb = (wid & 3) * 64;
#pragma unroll
  for (int n = 0; n < 4; ++n) {
    int col = n0 + wcb + n * 16 + lr;
    int lcol = col & 1023;
    float bv_ = bias[lcol];
    int h = lcol >> 6, d = lcol & 63;
#pragma unroll
    for (int m = 0; m < 8; ++m) {
      int r0 = m0 + wrb + m * 16 + lg * 4;
      int b_ = r0 >> 11, t_ = r0 & 2047;
      if (z < 2) {
        u16* dst = (z == 0) ? qo : ko;
#pragma unroll
        for (int i = 0; i < 4; ++i)
          dst[(((size_t)(b_ * NH + h)) * SEQT + t_ + i) * HS + d] = f2bf((acc[m][n][i] + bv_) * sc);
      } else {
        u16x4 v;
#pragma unroll
        for (int i = 0; i < 4; ++i) v[i] = f2bf(acc[m][n][i] + bv_);
        *(u16x4*)(vto + (((size_t)(b_ * NH + h)) * HS + d) * SEQT + t_) = v;
      }
    }
  }
}

// ---------------- output projection: [8192x1024] x [1024x1024], 128x256 tile -> fp32 ----------
__global__ __launch_bounds__(512, 2) void gemm_out(
    const u16* __restrict__ A, const u16* __restrict__ wot,
    const float* __restrict__ bo, float* __restrict__ out) {
  __shared__ __align__(16) u16 As[2][128 * 64];   // 32 KiB
  __shared__ __align__(16) u16 Bs[2][256 * 64];   // 64 KiB
  const int bid = blockIdx.x;
  const int swz = (bid & 7) * 32 + (bid >> 3);    // 256 = 8*32
  const int bm = swz >> 2, bn = swz & 3;
  const int m0 = bm * 128, n0 = bn * 256;
  const int lane = threadIdx.x & 63, wid = threadIdx.x >> 6;
  const int lr = lane & 15, lg = lane >> 4;

  f32x4 acc[4][4];
  const f32x4 zero = {0.f, 0.f, 0.f, 0.f};
#pragma unroll
  for (int m = 0; m < 4; ++m)
#pragma unroll
    for (int n = 0; n < 4; ++n) acc[m][n] = zero;

  gemm_core<128, 4>(A, wot, m0, n0, As, Bs, acc, lane, wid);

  const int wrb = (wid >> 2) * 64, wcb = (wid & 3) * 64;
#pragma unroll
  for (int n = 0; n < 4; ++n) {
    int col = n0 + wcb + n * 16 + lr;
    float bv_ = bo[col];
#pragma unroll
    for (int m = 0; m < 4; ++m) {
      int r0 = m0 + wrb + m * 16 + lg * 4;
#pragma unroll
      for (int i = 0; i < 4; ++i)
        out[(size_t)(r0 + i) * EMBED + col] = acc[m][n][i] + bv_;
    }
  }
}

// ---------------- flash attention v4 (unchanged from R4) ----------------
// 4 waves/block, QBLK=32/wave, KVBLK=64, single q-tile/block (1024 blocks,
// longest-first), 3 blocks/CU, 2-phase prefetch, XOR-swizzled K/V/P LDS,
// swapped QK^T, defer-max (THR=8 log2), setprio around MFMA clusters.
__global__ __launch_bounds__(256, 3) void flash(
    const u16* __restrict__ q, const u16* __restrict__ k,
    const u16* __restrict__ vt, u16* __restrict__ attnb) {
  __shared__ __align__(16) u16 Ks[2][4096];   // [kv=64][d=64] swizzled
  __shared__ __align__(16) u16 Vs[2][4096];   // [d=64][kv=64] swizzled
  __shared__ __align__(16) u16 Pl[4][2048];   // per-wave [q=32][kv=64] swizzled
  const int tid = threadIdx.x, lane = tid & 63, wid = tid >> 6;
  const int lr = lane & 15, lg = lane >> 4;
  const int g = blockIdx.x >> 6, pair = blockIdx.x & 63;  // same-pair blocks share an XCD
  const int qtile = 15 - g;                               // longest tiles dispatch first
  const u16* Qh = q + (size_t)pair * SEQT * HS;
  const u16* Kh = k + (size_t)pair * SEQT * HS;
  const u16* Vh = vt + (size_t)pair * HS * SEQT;

  const int sr0 = wid * 16 + (lane >> 3);
  const int sc0 = (lane & 7) ^ (sr0 & 7);
  const int sr1 = sr0 + 8;
  const int sc1 = (lane & 7) ^ (sr1 & 7);
  const int koff0 = sr0 * 64 + sc0 * 8;
  const int koff1 = sr1 * 64 + sc1 * 8;
  const size_t voff0 = (size_t)sr0 * SEQT + sc0 * 8;
  const size_t voff1 = (size_t)sr1 * SEQT + sc1 * 8;

  auto STAGE = [&](int t, int b) {
    const u16* Kb = Kh + (size_t)t * 4096;
    const u16* Vb = Vh + (size_t)t * 64;
    gload_lds16(Kb + koff0, &Ks[b][wid * 1024]);
    gload_lds16(Kb + koff1, &Ks[b][wid * 1024 + 512]);
    gload_lds16(Vb + voff0, &Vs[b][wid * 1024]);
    gload_lds16(Vb + voff1, &Vs[b][wid * 1024 + 512]);
  };

  const int b_ = pair >> 4, h = pair & 15;
  const int qw = qtile * 128 + wid * 32;

  bf16x8 qf[2][2];
#pragma unroll
  for (int nq = 0; nq < 2; ++nq)
#pragma unroll
    for (int ks = 0; ks < 2; ++ks)
      qf[nq][ks] = *(const bf16x8*)(Qh + (size_t)(qw + nq * 16 + lr) * HS + ks * 32 + lg * 8);

  f32x4 o[2][4];
  const f32x4 zero = {0.f, 0.f, 0.f, 0.f};
#pragma unroll
  for (int mr = 0; mr < 2; ++mr)
#pragma unroll
    for (int nd = 0; nd < 4; ++nd) o[mr][nd] = zero;
  float mrow[2] = {-1e30f, -1e30f}, lrow[2] = {0.f, 0.f};

  const int nt = (qtile + 1) * 2;
  int cur = 0;
  STAGE(0, 0);
  __syncthreads();

  for (int t = 0; t < nt; ++t) {
    if (t + 1 < nt) STAGE(t + 1, cur ^ 1);  // prefetch: completes under compute
    const int k0 = t * 64;

    bf16x8 kf[4][2];
#pragma unroll
    for (int mf = 0; mf < 4; ++mf) {
      const int row = mf * 16 + lr;
#pragma unroll
      for (int ks = 0; ks < 2; ++ks)
        kf[mf][ks] = *(const bf16x8*)(&Ks[cur][row * 64 + ((ks * 4 + lg) ^ (lr & 7)) * 8]);
    }
    // swapped QK^T: out col = q (lane&15), row = kv (lg*4+reg)
    f32x4 s[2][4];
    __builtin_amdgcn_s_setprio(1);
#pragma unroll
    for (int nq = 0; nq < 2; ++nq)
#pragma unroll
      for (int mf = 0; mf < 4; ++mf) {
        f32x4 a = zero;
        a = MFMA16(kf[mf][0], qf[nq][0], a);
        a = MFMA16(kf[mf][1], qf[nq][1], a);
        s[nq][mf] = a;
      }
    __builtin_amdgcn_s_setprio(0);
    bf16x8 vf[4][2];
#pragma unroll
    for (int nd = 0; nd < 4; ++nd) {
      const int row = nd * 16 + lr;
#pragma unroll
      for (int ks = 0; ks < 2; ++ks)
        vf[nd][ks] = *(const bf16x8*)(&Vs[cur][row * 64 + ((ks * 4 + lg) ^ (lr & 7)) * 8]);
    }

#pragma unroll
    for (int nq = 0; nq < 2; ++nq) {
      const int qmin = qw + nq * 16;
      if (k0 + 63 > qmin) {  // wave-uniform mask skip (diagonal tiles only)
        const int ql = qmin + lr;
#pragma unroll
        for (int mf = 0; mf < 4; ++mf) {
          const int kvb = k0 + mf * 16 + lg * 4;
#pragma unroll
          for (int r = 0; r < 4; ++r)
            if (kvb + r > ql) s[nq][mf][r] = -3.0e38f;
        }
      }
      float t0 = fmaxf(fmaxf(s[nq][0][0], s[nq][0][1]), fmaxf(s[nq][0][2], s[nq][0][3]));
      float t1 = fmaxf(fmaxf(s[nq][1][0], s[nq][1][1]), fmaxf(s[nq][1][2], s[nq][1][3]));
      float t2 = fmaxf(fmaxf(s[nq][2][0], s[nq][2][1]), fmaxf(s[nq][2][2], s[nq][2][3]));
      float t3 = fmaxf(fmaxf(s[nq][3][0], s[nq][3][1]), fmaxf(s[nq][3][2], s[nq][3][3]));
      float mx = fmaxf(fmaxf(t0, t1), fmaxf(t2, t3));
      mx = fmaxf(mx, __shfl_xor(mx, 16, 64));
      mx = fmaxf(mx, __shfl_xor(mx, 32, 64));
      // T13 defer-max: only rescale when a row's max grew past 8 (log2 domain)
      if (__any(mx > mrow[nq] + 8.0f)) {
        const float mn = fmaxf(mrow[nq], mx);
        const float al = exp2f(mrow[nq] - mn);
        mrow[nq] = mn;
        lrow[nq] *= al;
        float ao[4];
#pragma unroll
        for (int r = 0; r < 4; ++r) ao[r] = __shfl(al, lg * 4 + r, 64);
#pragma unroll
        for (int nd = 0; nd < 4; ++nd)
#pragma unroll
          for (int r = 0; r < 4; ++r) o[nq][nd][r] *= ao[r];
      }
      const float mn = mrow[nq];
      float rs = 0.f;
#pragma unroll
      for (int mf = 0; mf < 4; ++mf) {
        u16x4 pk;
#pragma unroll
        for (int r = 0; r < 4; ++r) {
          const float pv = exp2f(s[nq][mf][r] - mn);
          rs += pv;
          pk[r] = f2bf(pv);
        }
        *(u16x4*)(&Pl[wid][(nq * 16 + lr) * 64 +
                           (((2 * mf + (lg >> 1)) ^ (lr & 7)) * 8 + (lg & 1) * 4)]) = pk;
      }
      rs += __shfl_xor(rs, 16, 64);
      rs += __shfl_xor(rs, 32, 64);
      lrow[nq] += rs;
    }

    bf16x8 pa[2][2];
#pragma unroll
    for (int mr = 0; mr < 2; ++mr)
#pragma unroll
      for (int ks = 0; ks < 2; ++ks)
        pa[mr][ks] = *(const bf16x8*)(&Pl[wid][(mr * 16 + lr) * 64 + ((ks * 4 + lg) ^ (lr & 7)) * 8]);
    __builtin_amdgcn_s_setprio(1);
#pragma unroll
    for (int mr = 0; mr < 2; ++mr)
#pragma unroll
      for (int nd = 0; nd < 4; ++nd) {
        o[mr][nd] = MFMA16(pa[mr][0], vf[nd][0], o[mr][nd]);
        o[mr][nd] = MFMA16(pa[mr][1], vf[nd][1], o[mr][nd]);
      }
    __builtin_amdgcn_s_setprio(0);

    __syncthreads();  // drains prefetch vmcnt + publishes next buffer
    cur ^= 1;
  }

  // epilogue: attnb[b][t][h*64+d]
#pragma unroll
  for (int mr = 0; mr < 2; ++mr) {
    const float lv = 1.0f / lrow[mr];
    float li[4];
#pragma unroll
    for (int r = 0; r < 4; ++r) li[r] = __shfl(lv, lg * 4 + r, 64);
#pragma unroll
    for (int nd = 0; nd < 4; ++nd) {
      const int d = nd * 16 + lr;
#pragma unroll
      for (int r = 0; r < 4; ++r) {
        const int t_ = qw + mr * 16 + lg * 4 + r;
        attnb[((size_t)(b_ * SEQT + t_)) * EMBED + h * 64 + d] = f2bf(o[mr][nd][r] * li[r]);
      }
    }
  }
}

extern "C" void kernel_launch(void* const* d_in, const int* in_sizes, int n_in,
                              void* d_out, int out_size, void* d_ws, size_t ws_size,
                              hipStream_t stream) {
  const float* x  = (const float*)d_in[0];
  const float* wq = (const float*)d_in[1];
  const float* bq = (const float*)d_in[2];
  const float* wk = (const float*)d_in[3];
  const float* bk = (const float*)d_in[4];
  const float* wv = (const float*)d_in[5];
  const float* bv = (const float*)d_in[6];
  const float* wo = (const float*)d_in[7];
  const float* bo = (const float*)d_in[8];
  float* out = (float*)d_out;

  char* ws = (char*)d_ws;
  const size_t XB = 16777216;      // 8192*1024*2
  const size_t WB = 2097152;       // 1024*1024*2
  const size_t QB = 16777216;
  u16* xb     = (u16*)(ws);
  u16* wqkvbt = (u16*)(ws + XB);                    // fused [3072][1024] (wq|wk|wv)^T
  u16* wobt   = (u16*)(ws + XB + 3 * WB);
  u16* qb     = (u16*)(ws + XB + 4 * WB);
  u16* kb     = (u16*)(ws + XB + 4 * WB + QB);
  u16* vtb    = (u16*)(ws + XB + 4 * WB + 2 * QB);
  u16* attnb  = (u16*)(ws + XB + 4 * WB + 3 * QB);

  hipLaunchKernelGGL(cvt_x, dim3(8192), dim3(256), 0, stream, x, xb);
  hipLaunchKernelGGL(wtrans, dim3(32, 32, 4), dim3(32, 8), 0, stream,
                     wq, wk, wv, wo,
                     wqkvbt, wqkvbt + 1048576, wqkvbt + 2097152, wobt);
  hipLaunchKernelGGL(gemm_qkv, dim3(384), dim3(512), 0, stream,
                     xb, wqkvbt, bq, bk, bv, qb, kb, vtb);
  hipLaunchKernelGGL(flash, dim3(1024), dim3(256), 0, stream, qb, kb, vtb, attnb);
  hipLaunchKernelGGL(gemm_out, dim3(256), dim3(512), 0, stream, attnb, wobt, bo, out);
}